// Round 5
// baseline (223.099 us; speedup 1.0000x reference)
//
#include <hip/hip_runtime.h>

// IF neuron, multi-step, hard reset:
//   h_t = x_t + v_{t-1};  s_t = (h_t >= 1.0);  v_t = s_t ? 0 : h_t
//
// R11: R10 (NT loads) was the first structural win (~74-80 -> ~66-70 us):
// x-reads allocating in L3 cost more in read/write contention than their
// 50% hit rate saved. Now reads bypass L3 entirely -> the 256 MiB L3 is
// idle and the 128 MiB output fits in half of it. R8's plain-store test
// was run while reads still thrashed L3 (masked); rerun it clean:
// NT LOADS + PLAIN STORES. Stores complete at L3 (~34.5 TB/s) and write
// back lazily (partially after kernel end; the harness's 512 MiB fill
// sweep absorbs the drain outside our window). Critical path -> read-
// bound: 134 MB @ 6.3 TB/s ~ 21 us + store issue + latency slack.
//
// Fingerprints: FETCH ~131 MB (NT loads); WRITE during window < 131 MB
// (deferred writeback) if the mechanism engages.

typedef float v2f __attribute__((ext_vector_type(2)));

template <int T, int C>
__global__ __launch_bounds__(256) void if_node_mc_ntl_ps(
    const float* __restrict__ x,    // (T, N)
    const float* __restrict__ v0,   // (N,)
    float* __restrict__ out,        // (T, N)
    long q)                         // column stride in float2 elems = (N/2)/C
{
    long i = (long)blockIdx.x * blockDim.x + threadIdx.x;
    if (i >= q) return;

    const v2f* __restrict__ x2 = (const v2f*)x;
    v2f*       __restrict__ o2 = (v2f*)out;
    const v2f* __restrict__ vv = (const v2f*)v0;

    const long n2 = q * C;

    v2f v[C];
#pragma unroll
    for (int c = 0; c < C; ++c)
        v[c] = vv[i + (long)c * q];

#pragma unroll
    for (int t = 0; t < T; ++t) {
        v2f xv[C];
#pragma unroll
        for (int c = 0; c < C; ++c)
            xv[c] = __builtin_nontemporal_load(&x2[(long)t * n2 + i + (long)c * q]);

#pragma unroll
        for (int c = 0; c < C; ++c) {
            float hx = xv[c].x + v[c].x;
            float hy = xv[c].y + v[c].y;
            bool sx = hx >= 1.0f;   // == (h - 1.0f) >= 0 for all finite h
            bool sy = hy >= 1.0f;
            v2f s;
            s.x = sx ? 1.0f : 0.0f;
            s.y = sy ? 1.0f : 0.0f;
            v[c].x = sx ? 0.0f : hx;
            v[c].y = sy ? 0.0f : hy;
            // PLAIN store: lands in L3 (reads no longer contend for it),
            // lazy writeback off the kernel's critical path.
            o2[(long)t * n2 + i + (long)c * q] = s;
        }
    }
}

// Fallbacks for shapes the fast path doesn't cover.
__global__ __launch_bounds__(256) void if_node_f2_generic(
    const float* __restrict__ x, const float* __restrict__ v0,
    float* __restrict__ out, long n2, int T)
{
    long i = (long)blockIdx.x * blockDim.x + threadIdx.x;
    if (i >= n2) return;
    const v2f* x2 = (const v2f*)x;
    v2f*       o2 = (v2f*)out;
    v2f v = ((const v2f*)v0)[i];
    for (int t = 0; t < T; ++t) {
        v2f xv = x2[(long)t * n2 + i];
        float hx = xv.x + v.x;
        float hy = xv.y + v.y;
        bool sx = hx >= 1.0f;
        bool sy = hy >= 1.0f;
        v2f s;
        s.x = sx ? 1.0f : 0.0f;
        s.y = sy ? 1.0f : 0.0f;
        v.x = sx ? 0.0f : hx;
        v.y = sy ? 0.0f : hy;
        o2[(long)t * n2 + i] = s;
    }
}

__global__ __launch_bounds__(256) void if_node_scalar(
    const float* __restrict__ x, const float* __restrict__ v0,
    float* __restrict__ out, long n, int T)
{
    long i = (long)blockIdx.x * blockDim.x + threadIdx.x;
    if (i >= n) return;
    float v = v0[i];
    for (int t = 0; t < T; ++t) {
        float h = x[(long)t * n + i] + v;
        bool s = h >= 1.0f;
        out[(long)t * n + i] = s ? 1.0f : 0.0f;
        v = s ? 0.0f : h;
    }
}

extern "C" void kernel_launch(void* const* d_in, const int* in_sizes, int n_in,
                              void* d_out, int out_size, void* d_ws, size_t ws_size,
                              hipStream_t stream) {
    const float* x  = (const float*)d_in[0];   // (T, B, D) fp32
    const float* v0 = (const float*)d_in[1];   // (B, D) fp32
    float* out = (float*)d_out;                // (T, B, D) fp32

    long n = in_sizes[1];                      // B*D
    int  T = (int)(in_sizes[0] / n);           // 32

    int block = 256;
    constexpr int C = 4;
    if (T == 32 && (n % (2 * C)) == 0) {
        long n2 = n >> 1;          // float2 elements
        long q  = n2 / C;          // per-column float2 elements
        long grid = (q + block - 1) / block;
        if_node_mc_ntl_ps<32, C><<<dim3((unsigned)grid), dim3(block), 0, stream>>>(
            x, v0, out, q);
    } else if ((n & 1) == 0) {
        long n2 = n >> 1;
        long grid = (n2 + block - 1) / block;
        if_node_f2_generic<<<dim3((unsigned)grid), dim3(block), 0, stream>>>(
            x, v0, out, n2, T);
    } else {
        long grid = (n + block - 1) / block;
        if_node_scalar<<<dim3((unsigned)grid), dim3(block), 0, stream>>>(
            x, v0, out, n, T);
    }
}

// Round 6
// 219.464 us; speedup vs baseline: 1.0166x; 1.0166x over previous
//
#include <hip/hip_runtime.h>

// IF neuron, multi-step, hard reset:
//   h_t = x_t + v_{t-1};  s_t = (h_t >= 1.0);  v_t = s_t ? 0 : h_t
//
// R12: NT loads was the one real win (R10, ~74-80 -> ~67 us): x-reads
// allocating in L3 caused read/write contention. Store policy is
// confirmed neutral in the clean regime (R11 == R10). Remaining gap:
// ~67 us vs 42.5 us roofline (262 MB @ 6.3 TB/s). The 6.29 TB/s copy
// ubench that proves the mix can run at ~6.3 is FLOAT4; all NT-regime
// variants here were f2 (512 B/wave requests). If the L3-bypass path is
// request-rate-limited (every NT request traverses the fabric to HBM),
// halving request count at constant bytes is the lever.
//
// Single variable vs R10: f2 x C=4 -> f4 x C=2. Same 131072 threads,
// same 32 B/thread/t, NT loads + NT stores. Requests halve, width
// doubles.

typedef float v4f __attribute__((ext_vector_type(4)));
typedef float v2f __attribute__((ext_vector_type(2)));

template <int T, int C>
__global__ __launch_bounds__(256) void if_node_mc_f4nt(
    const float* __restrict__ x,    // (T, N)
    const float* __restrict__ v0,   // (N,)
    float* __restrict__ out,        // (T, N)
    long q)                         // column stride in float4 elems = (N/4)/C
{
    long i = (long)blockIdx.x * blockDim.x + threadIdx.x;
    if (i >= q) return;

    const v4f* __restrict__ x4 = (const v4f*)x;
    v4f*       __restrict__ o4 = (v4f*)out;
    const v4f* __restrict__ vv = (const v4f*)v0;

    const long n4 = q * C;

    v4f v[C];
#pragma unroll
    for (int c = 0; c < C; ++c)
        v[c] = vv[i + (long)c * q];

#pragma unroll
    for (int t = 0; t < T; ++t) {
        v4f xv[C];
#pragma unroll
        for (int c = 0; c < C; ++c)
            xv[c] = __builtin_nontemporal_load(&x4[(long)t * n4 + i + (long)c * q]);

#pragma unroll
        for (int c = 0; c < C; ++c) {
            v4f s;
#pragma unroll
            for (int e = 0; e < 4; ++e) {
                float h = xv[c][e] + v[c][e];
                bool sp = h >= 1.0f;   // == (h - 1.0f) >= 0 for all finite h
                s[e] = sp ? 1.0f : 0.0f;
                v[c][e] = sp ? 0.0f : h;
            }
            __builtin_nontemporal_store(s, &o4[(long)t * n4 + i + (long)c * q]);
        }
    }
}

// Fallbacks for shapes the fast path doesn't cover.
__global__ __launch_bounds__(256) void if_node_f2_generic(
    const float* __restrict__ x, const float* __restrict__ v0,
    float* __restrict__ out, long n2, int T)
{
    long i = (long)blockIdx.x * blockDim.x + threadIdx.x;
    if (i >= n2) return;
    const v2f* x2 = (const v2f*)x;
    v2f*       o2 = (v2f*)out;
    v2f v = ((const v2f*)v0)[i];
    for (int t = 0; t < T; ++t) {
        v2f xv = x2[(long)t * n2 + i];
        float hx = xv.x + v.x;
        float hy = xv.y + v.y;
        bool sx = hx >= 1.0f;
        bool sy = hy >= 1.0f;
        v2f s;
        s.x = sx ? 1.0f : 0.0f;
        s.y = sy ? 1.0f : 0.0f;
        v.x = sx ? 0.0f : hx;
        v.y = sy ? 0.0f : hy;
        o2[(long)t * n2 + i] = s;
    }
}

__global__ __launch_bounds__(256) void if_node_scalar(
    const float* __restrict__ x, const float* __restrict__ v0,
    float* __restrict__ out, long n, int T)
{
    long i = (long)blockIdx.x * blockDim.x + threadIdx.x;
    if (i >= n) return;
    float v = v0[i];
    for (int t = 0; t < T; ++t) {
        float h = x[(long)t * n + i] + v;
        bool s = h >= 1.0f;
        out[(long)t * n + i] = s ? 1.0f : 0.0f;
        v = s ? 0.0f : h;
    }
}

extern "C" void kernel_launch(void* const* d_in, const int* in_sizes, int n_in,
                              void* d_out, int out_size, void* d_ws, size_t ws_size,
                              hipStream_t stream) {
    const float* x  = (const float*)d_in[0];   // (T, B, D) fp32
    const float* v0 = (const float*)d_in[1];   // (B, D) fp32
    float* out = (float*)d_out;                // (T, B, D) fp32

    long n = in_sizes[1];                      // B*D
    int  T = (int)(in_sizes[0] / n);           // 32

    int block = 256;
    constexpr int C = 2;
    if (T == 32 && (n % (4 * C)) == 0) {
        long n4 = n >> 2;          // float4 elements
        long q  = n4 / C;          // per-column float4 elements
        long grid = (q + block - 1) / block;
        if_node_mc_f4nt<32, C><<<dim3((unsigned)grid), dim3(block), 0, stream>>>(
            x, v0, out, q);
    } else if ((n & 1) == 0) {
        long n2 = n >> 1;
        long grid = (n2 + block - 1) / block;
        if_node_f2_generic<<<dim3((unsigned)grid), dim3(block), 0, stream>>>(
            x, v0, out, n2, T);
    } else {
        long grid = (n + block - 1) / block;
        if_node_scalar<<<dim3((unsigned)grid), dim3(block), 0, stream>>>(
            x, v0, out, n, T);
    }
}